// Round 1
// baseline (482.339 us; speedup 1.0000x reference)
//
#include <hip/hip_runtime.h>
#include <stdint.h>

// Problem constants
#define B_   2
#define S_   2048
#define D_   2048
#define NH_  16
#define DH_  128
#define N3_  6144

typedef unsigned short u16;
typedef __bf16 bf16x8 __attribute__((ext_vector_type(8)));
typedef float  f32x4  __attribute__((ext_vector_type(4)));

__device__ __forceinline__ u16 f2bf(float f) {
  union { float f; unsigned u; } v; v.f = f;
  unsigned u = v.u;
  return (u16)((u + 0x7FFFu + ((u >> 16) & 1u)) >> 16);
}

// async global->LDS, 16B per lane; LDS dest must be wave-uniform-base + lane*16
#define GL2LDS(gsrc, ldst)                                                              \
  __builtin_amdgcn_global_load_lds((const __attribute__((address_space(1))) void*)(gsrc), \
      (__attribute__((address_space(3))) void*)(ldst), 16, 0, 0)

// ---------------- fp32 -> bf16 convert (vectorized) ----------------
__global__ void cvt_kernel(const float* __restrict__ in, u16* __restrict__ out, int n4) {
  int i = blockIdx.x * blockDim.x + threadIdx.x;
  int stride = gridDim.x * blockDim.x;
  for (; i < n4; i += stride) {
    float4 v = ((const float4*)in)[i];
    ushort4 o;
    o.x = f2bf(v.x); o.y = f2bf(v.y); o.z = f2bf(v.z); o.w = f2bf(v.w);
    ((ushort4*)out)[i] = o;
  }
}

// ---------------- fp32 [K][N] -> bf16 [N][K] transpose ----------------
__global__ void transpose_kernel(const float* __restrict__ in, u16* __restrict__ out,
                                 int K, int N) {
  __shared__ float tile[32][33];
  int tx = threadIdx.x, ty = threadIdx.y;
  int nx = blockIdx.x * 32, ky = blockIdx.y * 32;
#pragma unroll
  for (int j = 0; j < 32; j += 8)
    tile[ty + j][tx] = in[(size_t)(ky + ty + j) * N + nx + tx];
  __syncthreads();
#pragma unroll
  for (int j = 0; j < 32; j += 8)
    out[(size_t)(nx + ty + j) * K + ky + tx] = f2bf(tile[tx][ty + j]);
}

// ---------------- GEMM core: C[128x128] += A[rowmajor MxK] * BT[rowmajor NxK]^T ----
// 256 threads = 4 waves (2x2), per-wave 64x64, acc[4][4] of 16x16 frags, BK=64.
// LDS rows are 128B (64 bf16); XOR swizzle byte^=((row&7)<<4) applied on the
// global SOURCE during global_load_lds (linear LDS dest) and on fragment reads.
template <int KD>
__device__ __forceinline__ void gemm_core(const u16* __restrict__ A,
                                          const u16* __restrict__ BT,
                                          int m0, int n0, u16* As, u16* Bs,
                                          f32x4 acc[4][4]) {
  int t = threadIdx.x;
  int lane = t & 63, wv = t >> 6;
  int g = lane >> 4, lr = lane & 15;
  int wr = wv >> 1, wc = wv & 1;
  for (int k0 = 0; k0 < KD; k0 += 64) {
#pragma unroll
    for (int i = 0; i < 4; ++i) {
      int idx = i * 256 + t;
      int row = idx >> 3, slot = idx & 7;
      GL2LDS(A + (size_t)(m0 + row) * KD + k0 + ((slot ^ (row & 7)) * 8), As + idx * 8);
    }
#pragma unroll
    for (int i = 0; i < 4; ++i) {
      int idx = i * 256 + t;
      int row = idx >> 3, slot = idx & 7;
      GL2LDS(BT + (size_t)(n0 + row) * KD + k0 + ((slot ^ (row & 7)) * 8), Bs + idx * 8);
    }
    __syncthreads();
#pragma unroll
    for (int kk = 0; kk < 2; ++kk) {
      bf16x8 af[4], bfr[4];
#pragma unroll
      for (int m = 0; m < 4; ++m) {
        int r = wr * 64 + m * 16 + lr;
        af[m] = *reinterpret_cast<const bf16x8*>(As + r * 64 + ((((kk << 2) | g) ^ (r & 7)) * 8));
      }
#pragma unroll
      for (int n = 0; n < 4; ++n) {
        int r = wc * 64 + n * 16 + lr;
        bfr[n] = *reinterpret_cast<const bf16x8*>(Bs + r * 64 + ((((kk << 2) | g) ^ (r & 7)) * 8));
      }
#pragma unroll
      for (int m = 0; m < 4; ++m)
#pragma unroll
        for (int n = 0; n < 4; ++n)
          acc[m][n] = __builtin_amdgcn_mfma_f32_16x16x32_bf16(af[m], bfr[n], acc[m][n], 0, 0, 0);
    }
    __syncthreads();
  }
}

// ---------------- GEMM1: H @ Wattn + b -> scatter Q, K, V^T (bf16) ----------------
__global__ __launch_bounds__(256) void gemm_qkv_kernel(
    const u16* __restrict__ A, const u16* __restrict__ BT, const float* __restrict__ bias,
    u16* __restrict__ Qb, u16* __restrict__ Kb, u16* __restrict__ VTb) {
  __shared__ __attribute__((aligned(16))) u16 As[128 * 64];
  __shared__ __attribute__((aligned(16))) u16 Bs[128 * 64];
  f32x4 acc[4][4] = {};
  int m0 = blockIdx.y * 128, n0 = blockIdx.x * 128;
  gemm_core<2048>(A, BT, m0, n0, As, Bs, acc);
  int t = threadIdx.x, lane = t & 63, wv = t >> 6;
  int g = lane >> 4, lr = lane & 15, wr = wv >> 1, wc = wv & 1;
#pragma unroll
  for (int m = 0; m < 4; ++m) {
    int rowbase = m0 + wr * 64 + m * 16 + g * 4;
    int b = rowbase >> 11, s = rowbase & 2047;
#pragma unroll
    for (int n = 0; n < 4; ++n) {
      int col = n0 + wc * 64 + n * 16 + lr;
      float bv = bias[col];
      int sec = col >> 11;            // 0=Q 1=K 2=V
      int within = col & 2047;
      int h = within >> 7, d = within & 127;
      if (sec < 2) {
        u16* dst = (sec == 0 ? Qb : Kb) + ((size_t)(b * NH_ + h) * S_ + s) * DH_ + d;
#pragma unroll
        for (int r = 0; r < 4; ++r) dst[(size_t)r * DH_] = f2bf(acc[m][n][r] + bv);
      } else {
        u16* dst = VTb + ((size_t)(b * NH_ + h) * DH_ + d) * S_ + s;  // V transposed
        ushort4 pk;
        pk.x = f2bf(acc[m][n][0] + bv); pk.y = f2bf(acc[m][n][1] + bv);
        pk.z = f2bf(acc[m][n][2] + bv); pk.w = f2bf(acc[m][n][3] + bv);
        *reinterpret_cast<ushort4*>(dst) = pk;
      }
    }
  }
}

// ---------------- GEMM2: AO @ Wproj + b -> fp32 out ----------------
__global__ __launch_bounds__(256) void gemm_proj_kernel(
    const u16* __restrict__ A, const u16* __restrict__ BT, const float* __restrict__ bias,
    float* __restrict__ out) {
  __shared__ __attribute__((aligned(16))) u16 As[128 * 64];
  __shared__ __attribute__((aligned(16))) u16 Bs[128 * 64];
  f32x4 acc[4][4] = {};
  int m0 = blockIdx.y * 128, n0 = blockIdx.x * 128;
  gemm_core<2048>(A, BT, m0, n0, As, Bs, acc);
  int t = threadIdx.x, lane = t & 63, wv = t >> 6;
  int g = lane >> 4, lr = lane & 15, wr = wv >> 1, wc = wv & 1;
#pragma unroll
  for (int m = 0; m < 4; ++m) {
    int rowbase = m0 + wr * 64 + m * 16 + g * 4;
#pragma unroll
    for (int n = 0; n < 4; ++n) {
      int col = n0 + wc * 64 + n * 16 + lr;
      float bv = bias[col];
      float* dst = out + (size_t)rowbase * D_ + col;
#pragma unroll
      for (int r = 0; r < 4; ++r) dst[(size_t)r * D_] = acc[m][n][r] + bv;
    }
  }
}

// ---------------- flash attention: per block = (b,h) x 64 Q-rows -----------------
// 4 waves x 16 Q-rows. K-tile 64x128 and V^T-tile 128x64 staged via global_load_lds
// with XOR swizzle; online softmax; P routed through per-wave swizzled LDS.
__global__ __launch_bounds__(256) void attn_kernel(
    const u16* __restrict__ Qb, const u16* __restrict__ Kb, const u16* __restrict__ VTb,
    const float* __restrict__ mask, u16* __restrict__ AO) {
  __shared__ __attribute__((aligned(16))) u16 Ks[64 * 128];
  __shared__ __attribute__((aligned(16))) u16 Vs[128 * 64];
  __shared__ __attribute__((aligned(16))) u16 Ps[4][16 * 64];
  int t = threadIdx.x, w = t >> 6, lane = t & 63;
  int g = lane >> 4, lr = lane & 15;
  int qt = blockIdx.x, bh = blockIdx.y;
  int b = bh >> 4, h = bh & 15;
  const u16* Qh = Qb + (size_t)bh * S_ * DH_;
  const u16* Kh = Kb + (size_t)bh * S_ * DH_;
  const u16* Vh = VTb + (size_t)bh * DH_ * S_;
  int q0 = qt * 64 + w * 16;

  bf16x8 aq[4];
#pragma unroll
  for (int kk = 0; kk < 4; ++kk)
    aq[kk] = *reinterpret_cast<const bf16x8*>(Qh + (size_t)(q0 + lr) * DH_ + kk * 32 + g * 8);

  f32x4 oacc[8] = {};
  float m_r[4], l_r[4];
#pragma unroll
  for (int r = 0; r < 4; ++r) { m_r[r] = -1e30f; l_r[r] = 0.f; }
  const float sc = 0.08838834764831845f;  // 1/sqrt(128)

  for (int s0 = 0; s0 < S_; s0 += 64) {
#pragma unroll
    for (int i = 0; i < 4; ++i) {           // K tile: rows 256B, 16 slots
      int idx = i * 256 + t;
      int row = idx >> 4, slot = idx & 15;
      GL2LDS(Kh + (size_t)(s0 + row) * DH_ + ((slot ^ (row & 7)) * 8), Ks + idx * 8);
    }
#pragma unroll
    for (int i = 0; i < 4; ++i) {           // V^T tile: rows 128B, 8 slots
      int idx = i * 256 + t;
      int row = idx >> 3, slot = idx & 7;
      GL2LDS(Vh + (size_t)row * S_ + s0 + ((slot ^ (row & 7)) * 8), Vs + idx * 8);
    }
    __syncthreads();

    // QK^T: scores 16x64 per wave
    f32x4 sacc[4] = {};
#pragma unroll
    for (int kk = 0; kk < 4; ++kk) {
#pragma unroll
      for (int n = 0; n < 4; ++n) {
        int c = lr + 16 * n;
        bf16x8 bk = *reinterpret_cast<const bf16x8*>(
            Ks + c * 128 + ((((kk << 2) | g) ^ (c & 7)) * 8));
        sacc[n] = __builtin_amdgcn_mfma_f32_16x16x32_bf16(aq[kk], bk, sacc[n], 0, 0, 0);
      }
    }

    float bias_n[4];
#pragma unroll
    for (int n = 0; n < 4; ++n)
      bias_n[n] = (1.0f - mask[b * S_ + s0 + lr + 16 * n]) * -10000.0f;

#pragma unroll
    for (int r = 0; r < 4; ++r) {
      float sv[4];
#pragma unroll
      for (int n = 0; n < 4; ++n) sv[n] = sacc[n][r] * sc + bias_n[n];
      float mx = fmaxf(fmaxf(sv[0], sv[1]), fmaxf(sv[2], sv[3]));
#pragma unroll
      for (int off = 1; off < 16; off <<= 1) mx = fmaxf(mx, __shfl_xor(mx, off));
      float mnew = fmaxf(m_r[r], mx);
      float f = __expf(m_r[r] - mnew);
      m_r[r] = mnew;
      float sum = 0.f;
      u16 pb[4];
#pragma unroll
      for (int n = 0; n < 4; ++n) { float p = __expf(sv[n] - mnew); sum += p; pb[n] = f2bf(p); }
#pragma unroll
      for (int off = 1; off < 16; off <<= 1) sum += __shfl_xor(sum, off);
      l_r[r] = l_r[r] * f + sum;
#pragma unroll
      for (int no = 0; no < 8; ++no) oacc[no][r] *= f;
      int prow = g * 4 + r;
#pragma unroll
      for (int n = 0; n < 4; ++n) {
        int col = lr + 16 * n;
        Ps[w][prow * 64 + ((((col >> 3) ^ (prow & 7)) << 3) + (col & 7))] = pb[n];
      }
    }

    // PV: out 16x128 per wave
#pragma unroll
    for (int kk2 = 0; kk2 < 2; ++kk2) {
      bf16x8 ap = *reinterpret_cast<const bf16x8*>(
          &Ps[w][lr * 64 + ((((kk2 << 2) | g) ^ (lr & 7)) * 8)]);
#pragma unroll
      for (int no = 0; no < 8; ++no) {
        int d = lr + 16 * no;
        bf16x8 bv = *reinterpret_cast<const bf16x8*>(
            Vs + d * 64 + ((((kk2 << 2) | g) ^ (d & 7)) * 8));
        oacc[no] = __builtin_amdgcn_mfma_f32_16x16x32_bf16(ap, bv, oacc[no], 0, 0, 0);
      }
    }
    __syncthreads();
  }

#pragma unroll
  for (int r = 0; r < 4; ++r) {
    float inv = 1.0f / l_r[r];
    int qrow = q0 + g * 4 + r;
    u16* dst = AO + ((size_t)(b * S_ + qrow)) * D_ + h * DH_;
#pragma unroll
    for (int no = 0; no < 8; ++no) dst[lr + 16 * no] = f2bf(oacc[no][r] * inv);
  }
}

extern "C" void kernel_launch(void* const* d_in, const int* in_sizes, int n_in,
                              void* d_out, int out_size, void* d_ws, size_t ws_size,
                              hipStream_t stream) {
  const float* h_in   = (const float*)d_in[0];
  const float* mask   = (const float*)d_in[1];
  const float* w_attn = (const float*)d_in[2];
  const float* b_attn = (const float*)d_in[3];
  const float* w_proj = (const float*)d_in[4];
  const float* b_proj = (const float*)d_in[5];
  float* out = (float*)d_out;

  char* ws = (char*)d_ws;
  u16* Hb  = (u16*)(ws);                       // 16 MiB: H bf16 [4096][2048]
  u16* W1T = (u16*)(ws + 16777216);            // 24 MiB: Wattn^T bf16 [6144][2048]
  u16* W2T = (u16*)(ws + 41943040);            //  8 MiB: Wproj^T bf16 [2048][2048]
  u16* Qb  = (u16*)(ws + 50331648);            // 16 MiB: Q  [B][H][S][128]
  u16* Kb  = (u16*)(ws + 67108864);            // 16 MiB: K  [B][H][S][128]
  u16* VTb = (u16*)(ws + 83886080);            // 16 MiB: V^T [B][H][128][S]
  u16* AO  = Hb;  // reuse H region for attention output (H dead after gemm_qkv)

  cvt_kernel<<<2048, 256, 0, stream>>>(h_in, Hb, (B_ * S_ * D_) / 4);
  dim3 tb(32, 8);
  transpose_kernel<<<dim3(N3_ / 32, D_ / 32), tb, 0, stream>>>(w_attn, W1T, D_, N3_);
  transpose_kernel<<<dim3(D_ / 32, D_ / 32), tb, 0, stream>>>(w_proj, W2T, D_, D_);
  gemm_qkv_kernel<<<dim3(N3_ / 128, (B_ * S_) / 128), 256, 0, stream>>>(
      Hb, W1T, b_attn, Qb, Kb, VTb);
  attn_kernel<<<dim3(S_ / 64, B_ * NH_), 256, 0, stream>>>(Qb, Kb, VTb, mask, AO);
  gemm_proj_kernel<<<dim3(D_ / 128, (B_ * S_) / 128), 256, 0, stream>>>(AO, W2T, b_proj, out);
}

// Round 2
// 468.170 us; speedup vs baseline: 1.0303x; 1.0303x over previous
//
#include <hip/hip_runtime.h>
#include <stdint.h>

// Problem constants
#define B_   2
#define S_   2048
#define D_   2048
#define NH_  16
#define DH_  128
#define N3_  6144

typedef unsigned short u16;
typedef __bf16 bf16x8 __attribute__((ext_vector_type(8)));
typedef float  f32x4  __attribute__((ext_vector_type(4)));

#define QSCALE   (0.08838834764831845f * 1.4426950408889634f)  // 1/sqrt(128) * log2(e)
#define BIASF    (-10000.0f * 1.4426950408889634f)

__device__ __forceinline__ u16 f2bf(float f) {
  union { float f; unsigned u; } v; v.f = f;
  unsigned u = v.u;
  return (u16)((u + 0x7FFFu + ((u >> 16) & 1u)) >> 16);
}

__device__ __forceinline__ float fast_exp2(float x) {
  float r;
  asm("v_exp_f32 %0, %1" : "=v"(r) : "v"(x));
  return r;
}

// async global->LDS, 16B per lane; LDS dest must be wave-uniform-base + lane*16
#define GL2LDS(gsrc, ldst)                                                              \
  __builtin_amdgcn_global_load_lds((const __attribute__((address_space(1))) void*)(gsrc), \
      (__attribute__((address_space(3))) void*)(ldst), 16, 0, 0)

// XCD-aware block swizzle: contiguous logical chunk per XCD. Requires total%8==0.
__device__ __forceinline__ int swz_id() {
  int id = blockIdx.y * gridDim.x + blockIdx.x;
  int cpx = (gridDim.x * gridDim.y) >> 3;
  return (id & 7) * cpx + (id >> 3);
}

// ---------------- fp32 -> bf16 convert (vectorized) ----------------
__global__ void cvt_kernel(const float* __restrict__ in, u16* __restrict__ out, int n4) {
  int i = blockIdx.x * blockDim.x + threadIdx.x;
  int stride = gridDim.x * blockDim.x;
  for (; i < n4; i += stride) {
    float4 v = ((const float4*)in)[i];
    ushort4 o;
    o.x = f2bf(v.x); o.y = f2bf(v.y); o.z = f2bf(v.z); o.w = f2bf(v.w);
    ((ushort4*)out)[i] = o;
  }
}

// ---------------- fp32 [K][N] -> bf16 [N][K] transpose ----------------
__global__ void transpose_kernel(const float* __restrict__ in, u16* __restrict__ out,
                                 int K, int N) {
  __shared__ float tile[32][33];
  int tx = threadIdx.x, ty = threadIdx.y;
  int nx = blockIdx.x * 32, ky = blockIdx.y * 32;
#pragma unroll
  for (int j = 0; j < 32; j += 8)
    tile[ty + j][tx] = in[(size_t)(ky + ty + j) * N + nx + tx];
  __syncthreads();
#pragma unroll
  for (int j = 0; j < 32; j += 8)
    out[(size_t)(nx + ty + j) * K + ky + tx] = f2bf(tile[tx][ty + j]);
}

// ---------------- GEMM core: C[128x128] += A[rowmajor MxK] * BT[rowmajor NxK]^T ----
// 256 threads = 4 waves (2x2), per-wave 64x64, acc[4][4] of 16x16 frags, BK=64.
// LDS rows are 128B (64 bf16); XOR swizzle byte^=((row&7)<<4) applied on the
// global SOURCE during global_load_lds (linear LDS dest) and on fragment reads.
template <int KD>
__device__ __forceinline__ void gemm_core(const u16* __restrict__ A,
                                          const u16* __restrict__ BT,
                                          int m0, int n0, u16* As, u16* Bs,
                                          f32x4 acc[4][4]) {
  int t = threadIdx.x;
  int lane = t & 63, wv = t >> 6;
  int g = lane >> 4, lr = lane & 15;
  int wr = wv >> 1, wc = wv & 1;
  for (int k0 = 0; k0 < KD; k0 += 64) {
#pragma unroll
    for (int i = 0; i < 4; ++i) {
      int idx = i * 256 + t;
      int row = idx >> 3, slot = idx & 7;
      GL2LDS(A + (size_t)(m0 + row) * KD + k0 + ((slot ^ (row & 7)) * 8), As + idx * 8);
    }
#pragma unroll
    for (int i = 0; i < 4; ++i) {
      int idx = i * 256 + t;
      int row = idx >> 3, slot = idx & 7;
      GL2LDS(BT + (size_t)(n0 + row) * KD + k0 + ((slot ^ (row & 7)) * 8), Bs + idx * 8);
    }
    __syncthreads();
#pragma unroll
    for (int kk = 0; kk < 2; ++kk) {
      bf16x8 af[4], bfr[4];
#pragma unroll
      for (int m = 0; m < 4; ++m) {
        int r = wr * 64 + m * 16 + lr;
        af[m] = *reinterpret_cast<const bf16x8*>(As + r * 64 + ((((kk << 2) | g) ^ (r & 7)) * 8));
      }
#pragma unroll
      for (int n = 0; n < 4; ++n) {
        int r = wc * 64 + n * 16 + lr;
        bfr[n] = *reinterpret_cast<const bf16x8*>(Bs + r * 64 + ((((kk << 2) | g) ^ (r & 7)) * 8));
      }
#pragma unroll
      for (int m = 0; m < 4; ++m)
#pragma unroll
        for (int n = 0; n < 4; ++n)
          acc[m][n] = __builtin_amdgcn_mfma_f32_16x16x32_bf16(af[m], bfr[n], acc[m][n], 0, 0, 0);
    }
    __syncthreads();
  }
}

// ---------------- GEMM1: H @ Wattn + b -> scatter Q (prescaled), K, V^T ----------------
__global__ __launch_bounds__(256) void gemm_qkv_kernel(
    const u16* __restrict__ A, const u16* __restrict__ BT, const float* __restrict__ bias,
    u16* __restrict__ Qb, u16* __restrict__ Kb, u16* __restrict__ VTb) {
  __shared__ __attribute__((aligned(16))) u16 As[128 * 64];
  __shared__ __attribute__((aligned(16))) u16 Bs[128 * 64];
  f32x4 acc[4][4] = {};
  int sw = swz_id();
  int n0 = (sw % gridDim.x) * 128, m0 = (sw / gridDim.x) * 128;
  gemm_core<2048>(A, BT, m0, n0, As, Bs, acc);
  int t = threadIdx.x, lane = t & 63, wv = t >> 6;
  int g = lane >> 4, lr = lane & 15, wr = wv >> 1, wc = wv & 1;
#pragma unroll
  for (int m = 0; m < 4; ++m) {
    int rowbase = m0 + wr * 64 + m * 16 + g * 4;
    int b = rowbase >> 11, s = rowbase & 2047;
#pragma unroll
    for (int n = 0; n < 4; ++n) {
      int col = n0 + wc * 64 + n * 16 + lr;
      float bv = bias[col];
      int sec = col >> 11;            // 0=Q 1=K 2=V
      int within = col & 2047;
      int h = within >> 7, d = within & 127;
      if (sec < 2) {
        float mult = (sec == 0) ? QSCALE : 1.0f;   // fold 1/sqrt(dh)*log2e into Q
        u16* dst = (sec == 0 ? Qb : Kb) + ((size_t)(b * NH_ + h) * S_ + s) * DH_ + d;
#pragma unroll
        for (int r = 0; r < 4; ++r) dst[(size_t)r * DH_] = f2bf((acc[m][n][r] + bv) * mult);
      } else {
        u16* dst = VTb + ((size_t)(b * NH_ + h) * DH_ + d) * S_ + s;  // V transposed
        ushort4 pk;
        pk.x = f2bf(acc[m][n][0] + bv); pk.y = f2bf(acc[m][n][1] + bv);
        pk.z = f2bf(acc[m][n][2] + bv); pk.w = f2bf(acc[m][n][3] + bv);
        *reinterpret_cast<ushort4*>(dst) = pk;
      }
    }
  }
}

// ---------------- GEMM2: AO @ Wproj + b -> fp32 out ----------------
__global__ __launch_bounds__(256) void gemm_proj_kernel(
    const u16* __restrict__ A, const u16* __restrict__ BT, const float* __restrict__ bias,
    float* __restrict__ out) {
  __shared__ __attribute__((aligned(16))) u16 As[128 * 64];
  __shared__ __attribute__((aligned(16))) u16 Bs[128 * 64];
  f32x4 acc[4][4] = {};
  int sw = swz_id();
  int n0 = (sw % gridDim.x) * 128, m0 = (sw / gridDim.x) * 128;
  gemm_core<2048>(A, BT, m0, n0, As, Bs, acc);
  int t = threadIdx.x, lane = t & 63, wv = t >> 6;
  int g = lane >> 4, lr = lane & 15, wr = wv >> 1, wc = wv & 1;
#pragma unroll
  for (int m = 0; m < 4; ++m) {
    int rowbase = m0 + wr * 64 + m * 16 + g * 4;
#pragma unroll
    for (int n = 0; n < 4; ++n) {
      int col = n0 + wc * 64 + n * 16 + lr;
      float bv = bias[col];
      float* dst = out + (size_t)rowbase * D_ + col;
#pragma unroll
      for (int r = 0; r < 4; ++r) dst[(size_t)r * D_] = acc[m][n][r] + bv;
    }
  }
}

// ---------------- flash attention v2: pipelined K/V double-buffer -----------------
// Block = (b,h) x 64 Q rows, 4 waves x 16 rows. K/V tiles (64x128 / 128x64) double-
// buffered in LDS; next tile's global_load_lds issued before current compute, with
// counted s_waitcnt vmcnt(8) + raw s_barrier (no vmcnt(0) drain mid-loop).
// Softmax in log2 domain (Q prescaled); defer-max (THR=8); per-lane partial l.
__global__ __launch_bounds__(256) void attn_kernel(
    const u16* __restrict__ Qb, const u16* __restrict__ Kb, const u16* __restrict__ VTb,
    const float* __restrict__ mask, u16* __restrict__ AO) {
  __shared__ __attribute__((aligned(16))) u16 Ks[2][64 * 128];
  __shared__ __attribute__((aligned(16))) u16 Vs[2][128 * 64];
  __shared__ __attribute__((aligned(16))) u16 Ps[4][16 * 64];
  __shared__ float bias_lds[S_];

  int t = threadIdx.x, w = t >> 6, lane = t & 63;
  int g = lane >> 4, lr = lane & 15;
  int sw = swz_id();                 // group same-(b,h) blocks per XCD
  int qt = sw & 31, bh = sw >> 5;
  int b = bh >> 4;
  const u16* Qh = Qb + (size_t)bh * S_ * DH_;
  const u16* Kh = Kb + (size_t)bh * S_ * DH_;
  const u16* Vh = VTb + (size_t)bh * DH_ * S_;
  int q0 = qt * 64 + w * 16;

  // mask -> additive bias (log2 units), staged once per block
  for (int i = t; i < S_; i += 256)
    bias_lds[i] = (1.0f - mask[b * S_ + i]) * BIASF;

  bf16x8 aq[4];
#pragma unroll
  for (int kk = 0; kk < 4; ++kk)
    aq[kk] = *reinterpret_cast<const bf16x8*>(Qh + (size_t)(q0 + lr) * DH_ + kk * 32 + g * 8);

  f32x4 oacc[8] = {};
  float m_r[4], l_r[4];
#pragma unroll
  for (int r = 0; r < 4; ++r) { m_r[r] = -1e30f; l_r[r] = 0.f; }

  __syncthreads();   // bias_lds visible; full drain (Q frag loads retired)

#define STAGE_KV(buf, s0base)                                                    \
  {                                                                              \
    _Pragma("unroll")                                                            \
    for (int i = 0; i < 4; ++i) {                                                \
      int idx = i * 256 + t;                                                     \
      int row = idx >> 4, slot = idx & 15;                                       \
      GL2LDS(Kh + (size_t)((s0base) + row) * DH_ + ((slot ^ (row & 7)) * 8),     \
             &Ks[buf][idx * 8]);                                                 \
    }                                                                            \
    _Pragma("unroll")                                                            \
    for (int i = 0; i < 4; ++i) {                                                \
      int idx = i * 256 + t;                                                     \
      int row = idx >> 3, slot = idx & 7;                                        \
      GL2LDS(Vh + (size_t)row * S_ + (s0base) + ((slot ^ (row & 7)) * 8),        \
             &Vs[buf][idx * 8]);                                                 \
    }                                                                            \
  }

  STAGE_KV(0, 0);
  const int NT = S_ / 64;
  for (int it = 0; it < NT; ++it) {
    int cur = it & 1;
    if (it + 1 < NT) {
      STAGE_KV(cur ^ 1, (it + 1) * 64);
      asm volatile("s_waitcnt vmcnt(8)" ::: "memory");  // current tile landed
    } else {
      asm volatile("s_waitcnt vmcnt(0)" ::: "memory");
    }
    __builtin_amdgcn_s_barrier();
    __builtin_amdgcn_sched_barrier(0);

    // QK^T: scores 16x64 per wave (log2-domain: Q prescaled)
    f32x4 sacc[4] = {};
#pragma unroll
    for (int kk = 0; kk < 4; ++kk) {
#pragma unroll
      for (int n = 0; n < 4; ++n) {
        int c = lr + 16 * n;
        bf16x8 bk = *reinterpret_cast<const bf16x8*>(
            &Ks[cur][c * 128 + ((((kk << 2) | g) ^ (c & 7)) * 8)]);
        sacc[n] = __builtin_amdgcn_mfma_f32_16x16x32_bf16(aq[kk], bk, sacc[n], 0, 0, 0);
      }
    }

    int s0 = it * 64;
    float sv[4][4], mx[4];
#pragma unroll
    for (int r = 0; r < 4; ++r) {
#pragma unroll
      for (int n = 0; n < 4; ++n) sv[r][n] = sacc[n][r] + bias_lds[s0 + lr + 16 * n];
      float m2 = fmaxf(fmaxf(sv[r][0], sv[r][1]), fmaxf(sv[r][2], sv[r][3]));
#pragma unroll
      for (int off = 1; off < 16; off <<= 1) m2 = fmaxf(m2, __shfl_xor(m2, off));
      mx[r] = m2;
    }
    // defer-max: rescale only if some row grew by >8 (log2 units -> p <= 256)
    float gmax = fmaxf(fmaxf(mx[0] - m_r[0], mx[1] - m_r[1]),
                       fmaxf(mx[2] - m_r[2], mx[3] - m_r[3]));
    if (__any(gmax > 8.f)) {
#pragma unroll
      for (int r = 0; r < 4; ++r) {
        float mnew = fmaxf(m_r[r], mx[r]);
        float f = fast_exp2(m_r[r] - mnew);
        m_r[r] = mnew;
        l_r[r] *= f;
#pragma unroll
        for (int no = 0; no < 8; ++no) oacc[no][r] *= f;
      }
    }
#pragma unroll
    for (int r = 0; r < 4; ++r) {
      int prow = g * 4 + r;
#pragma unroll
      for (int n = 0; n < 4; ++n) {
        float p = fast_exp2(sv[r][n] - m_r[r]);
        l_r[r] += p;                         // per-lane partial row-sum
        int col = lr + 16 * n;
        Ps[w][prow * 64 + ((((col >> 3) ^ (prow & 7)) << 3) + (col & 7))] = f2bf(p);
      }
    }

    // PV: out 16x128 per wave
#pragma unroll
    for (int kk2 = 0; kk2 < 2; ++kk2) {
      bf16x8 ap = *reinterpret_cast<const bf16x8*>(
          &Ps[w][lr * 64 + ((((kk2 << 2) | g) ^ (lr & 7)) * 8)]);
#pragma unroll
      for (int no = 0; no < 8; ++no) {
        int d = lr + 16 * no;
        bf16x8 bv = *reinterpret_cast<const bf16x8*>(
            &Vs[cur][d * 64 + ((((kk2 << 2) | g) ^ (d & 7)) * 8)]);
        oacc[no] = __builtin_amdgcn_mfma_f32_16x16x32_bf16(ap, bv, oacc[no], 0, 0, 0);
      }
    }
    __builtin_amdgcn_sched_barrier(0);
    __builtin_amdgcn_s_barrier();
  }
#undef STAGE_KV

#pragma unroll
  for (int r = 0; r < 4; ++r) {
    float s = l_r[r];
#pragma unroll
    for (int off = 1; off < 16; off <<= 1) s += __shfl_xor(s, off);
    float inv = 1.0f / s;
    int qrow = q0 + g * 4 + r;
    int h = bh & 15;
    u16* dst = AO + ((size_t)(b * S_ + qrow)) * D_ + h * DH_;
#pragma unroll
    for (int no = 0; no < 8; ++no) dst[lr + 16 * no] = f2bf(oacc[no][r] * inv);
  }
}

extern "C" void kernel_launch(void* const* d_in, const int* in_sizes, int n_in,
                              void* d_out, int out_size, void* d_ws, size_t ws_size,
                              hipStream_t stream) {
  const float* h_in   = (const float*)d_in[0];
  const float* mask   = (const float*)d_in[1];
  const float* w_attn = (const float*)d_in[2];
  const float* b_attn = (const float*)d_in[3];
  const float* w_proj = (const float*)d_in[4];
  const float* b_proj = (const float*)d_in[5];
  float* out = (float*)d_out;

  char* ws = (char*)d_ws;
  u16* Hb  = (u16*)(ws);                       // 16 MiB: H bf16 [4096][2048]
  u16* W1T = (u16*)(ws + 16777216);            // 24 MiB: Wattn^T bf16 [6144][2048]
  u16* W2T = (u16*)(ws + 41943040);            //  8 MiB: Wproj^T bf16 [2048][2048]
  u16* Qb  = (u16*)(ws + 50331648);            // 16 MiB: Q (prescaled) [B][H][S][128]
  u16* Kb  = (u16*)(ws + 67108864);            // 16 MiB: K  [B][H][S][128]
  u16* VTb = (u16*)(ws + 83886080);            // 16 MiB: V^T [B][H][128][S]
  u16* AO  = Hb;  // reuse H region for attention output (H dead after gemm_qkv)

  cvt_kernel<<<2048, 256, 0, stream>>>(h_in, Hb, (B_ * S_ * D_) / 4);
  dim3 tb(32, 8);
  transpose_kernel<<<dim3(N3_ / 32, D_ / 32), tb, 0, stream>>>(w_attn, W1T, D_, N3_);
  transpose_kernel<<<dim3(D_ / 32, D_ / 32), tb, 0, stream>>>(w_proj, W2T, D_, D_);
  gemm_qkv_kernel<<<dim3(N3_ / 128, (B_ * S_) / 128), 256, 0, stream>>>(
      Hb, W1T, b_attn, Qb, Kb, VTb);
  attn_kernel<<<dim3(S_ / 64, B_ * NH_), 256, 0, stream>>>(Qb, Kb, VTb, mask, AO);
  gemm_proj_kernel<<<dim3(D_ / 128, (B_ * S_) / 128), 256, 0, stream>>>(AO, W2T, b_proj, out);
}